// Round 8
// baseline (1890.911 us; speedup 1.0000x reference)
//
#include <hip/hip_runtime.h>

// LocallyConnected2d: x [64,32,64,64] f32, w [1,64,32,62,62,9] f32 -> out [64,64,62,62] f32
// out[b,o,loc] = sum_{i,k} x[b,i,oh+k/3,ow+k%3] * w[o,i,loc,k]
//
// Round-8 = round-7 structure (no LDS, no barriers, W direct-to-VGPR) with:
//  - amdgpu_waves_per_eu(2,2): pins the allocator's occupancy TARGET (r4-r7 all
//    allocated for 2x the declared min -> spilled; VGPR was cap/2 every round).
//    256-VGPR budget for a ~230-reg live set -> zero spill.
//  - back to the [8 b][8 loc]-per-o C-tile (acc 64 regs): 1152 FMA-instr per wave
//    per channel, W (72 regs) amortized 2x vs round-7.
//  - sched_barrier(0) per r-section + channel top: whole channel is one BB after
//    unroll; fences stop the scheduler from batching all 78 loads (pressure spike).

#define OWDIM 62
#define LOCS 3844
#define WSI 34596u      // 62*62*9 floats per (o,i)
#define XM 131072u      // 32*64*64 per-batch x elements

__device__ __forceinline__ float f4get(const float4 v, int j) {
    return j == 0 ? v.x : j == 1 ? v.y : j == 2 ? v.z : v.w;
}
__device__ __forceinline__ void fma4(float4& a, float s, const float4 x) {
    a.x = fmaf(s, x.x, a.x);
    a.y = fmaf(s, x.y, a.y);
    a.z = fmaf(s, x.z, a.z);
    a.w = fmaf(s, x.w, a.w);
}

__global__ void lc2d_transpose_x(const float* __restrict__ x, float* __restrict__ xT) {
    __shared__ float tile[64][65];
    const int m0 = blockIdx.x * 64;
    const int t = threadIdx.x;
    const int c = t & 63, q = t >> 6;
#pragma unroll
    for (int jj = 0; jj < 16; ++jj) {
        const int b = q * 16 + jj;
        tile[c][b] = x[(size_t)b * XM + (size_t)(m0 + c)];
    }
    __syncthreads();
#pragma unroll
    for (int jj = 0; jj < 16; ++jj) {
        const int m = q * 16 + jj;
        xT[(size_t)(m0 + m) * 64u + (size_t)c] = tile[m][c];
    }
}

// static select of weight element (l, k) from the 18-float4 run (l,k compile-time)
#define WGET(l, k) f4get(W[((l) * 9 + (k)) >> 2], ((l) * 9 + (k)) & 3)

__global__ __launch_bounds__(256)
__attribute__((amdgpu_waves_per_eu(2, 2)))
void lc2d_main(const float* __restrict__ w,
               const float* __restrict__ xT,
               float* __restrict__ out) {
    // grid 992 = 8 XCD chunks x 124; t = (ohalf, oh, ow-tile), ow-tile fastest ->
    // adjacent weight runs (contiguous in memory) stream on the same XCD.
    const int bid = blockIdx.x;
    const int t = (bid & 7) * 124 + (bid >> 3);
    const int ohalf = (t >= 496) ? 1 : 0;
    const int rem = t - ohalf * 496;
    const int oh = rem >> 3;
    const int t8 = rem & 7;
    const int ow0 = (t8 < 7) ? (t8 << 3) : 54;   // last tile overlaps: no guards
    const int loc0 = oh * OWDIM + ow0;

    const int lane = threadIdx.x & 63;
    const int wave = __builtin_amdgcn_readfirstlane((int)(threadIdx.x >> 6));
    const int bg = lane & 7;      // b-octet: b = bg*8 + db, db 0..7 (accA/accB)
    const int og = lane >> 3;     // o within wave's octet
    const int o = ohalf * 32 + wave * 8 + og;

    const float* wbase = w + (size_t)o * 32u * WSI + (size_t)loc0 * 9u;
    const float* xbase = xT + (size_t)(bg * 8);

    float4 accA[8], accB[8];
#pragma unroll
    for (int l = 0; l < 8; ++l) {
        accA[l] = make_float4(0.f, 0.f, 0.f, 0.f);
        accB[l] = make_float4(0.f, 0.f, 0.f, 0.f);
    }

#pragma unroll 1
    for (int i = 0; i < 32; ++i) {
        __builtin_amdgcn_sched_barrier(0);   // channel fence: no cross-channel hoists
        // weight run for (o, i, loc0..loc0+7): 72 contiguous floats -> 18 dwordx4
        // (4B-aligned dwordx4: proven correct on this HW in round 7)
        const float* wr = wbase + (size_t)i * WSI;
        float4 W[18];
#pragma unroll
        for (int j = 0; j < 18; ++j) W[j] = *(const float4*)(wr + 4 * j);

#pragma unroll
        for (int r = 0; r < 3; ++r) {
            const float* xp = xbase + ((size_t)i * 4096u + (size_t)((oh + r) * 64 + ow0)) * 64u;
            float4 Xa[10], Xb[10];
#pragma unroll
            for (int m = 0; m < 10; ++m) {
                Xa[m] = *(const float4*)(xp + (size_t)(m * 64));
                Xb[m] = *(const float4*)(xp + (size_t)(m * 64) + 4);
            }
            // 384 fp32-FMA instructions for this row
#pragma unroll
            for (int m = 0; m < 10; ++m) {
#pragma unroll
                for (int cc = 0; cc < 3; ++cc) {
                    const int l = m - cc;            // loc' hit by col m at tap-col cc
                    if (l >= 0 && l < 8) {
                        const float ws = WGET(l, r * 3 + cc);
                        fma4(accA[l], ws, Xa[m]);
                        fma4(accB[l], ws, Xb[m]);
                    }
                }
            }
            __builtin_amdgcn_sched_barrier(0);   // section fence: cap in-flight loads
        }
    }

    // stores: per (b,o) an 8-float loc run -> 4x float2 (loc0 even -> 8B aligned)
#define ACCV(db, l) ((db) < 4 ? f4get(accA[(l)], (db)) : f4get(accB[(l)], (db) - 4))
#pragma unroll
    for (int db = 0; db < 8; ++db) {
        float* po = out + (size_t)((bg * 8 + db) * 64 + o) * (size_t)LOCS + (size_t)loc0;
        *(float2*)(po + 0) = make_float2(ACCV(db, 0), ACCV(db, 1));
        *(float2*)(po + 2) = make_float2(ACCV(db, 2), ACCV(db, 3));
        *(float2*)(po + 4) = make_float2(ACCV(db, 4), ACCV(db, 5));
        *(float2*)(po + 6) = make_float2(ACCV(db, 6), ACCV(db, 7));
    }
#undef ACCV
}

extern "C" void kernel_launch(void* const* d_in, const int* in_sizes, int n_in,
                              void* d_out, int out_size, void* d_ws, size_t ws_size,
                              hipStream_t stream) {
    const float* x = (const float*)d_in[0];   // 64*32*64*64
    const float* w = (const float*)d_in[1];   // 1*64*32*62*62*9
    float* out = (float*)d_out;               // 64*64*62*62
    float* xT = (float*)d_ws;                 // 32 MiB scratch

    lc2d_transpose_x<<<dim3(XM / 64), dim3(256), 0, stream>>>(x, xT);
    lc2d_main<<<dim3(992), dim3(256), 0, stream>>>(w, xT, out);
}

// Round 9
// 521.542 us; speedup vs baseline: 3.6256x; 3.6256x over previous
//
#include <hip/hip_runtime.h>

// LocallyConnected2d: x [64,32,64,64] f32, w [1,64,32,62,62,9] f32 -> out [64,64,62,62] f32
// out[b,o,loc] = sum_{i,k} x[b,i,oh+k/3,ow+k%3] * w[o,i,loc,k]
//
// Round-9 = round-6 dataflow, live-set fitted to the allocator's stubborn 128-VGPR
// target (r4-r8: it allocates 128 regardless of launch_bounds/waves_per_eu attrs):
//   acc 64 + wq 24 + x-ring 24 + addressing ~14 = ~126 regs.
//  - x consumed column-at-a-time via a 3-slot STATIC ring (fully unrolled -> all
//    indices compile-time; rule-#20 safe), 2-deep prefetch covers L1 latency.
//  - per-wave self-staged weight dbuf via global_load_lds (lane-linear [k][og*8+l]),
//    no barriers; one vmcnt(0) per channel.
//  - sched_barrier(0) per column + per r-section: freezes liveness at the planned
//    ~126 (r6 died because the scheduler batched 20 x-loads -> 168 live -> AGPR mush).

#define OWDIM 62
#define LOCS 3844
#define WSI 34596u      // 62*62*9 floats per (o,i)
#define XM 131072u      // 32*64*64 per-batch x elements

__device__ __forceinline__ float f4get(const float4 v, int j) {
    return j == 0 ? v.x : j == 1 ? v.y : j == 2 ? v.z : v.w;
}
__device__ __forceinline__ void fma4(float4& a, float s, const float4 x) {
    a.x = fmaf(s, x.x, a.x);
    a.y = fmaf(s, x.y, a.y);
    a.z = fmaf(s, x.z, a.z);
    a.w = fmaf(s, x.w, a.w);
}

__global__ void lc2d_transpose_x(const float* __restrict__ x, float* __restrict__ xT) {
    __shared__ float tile[64][65];
    const int m0 = blockIdx.x * 64;
    const int t = threadIdx.x;
    const int c = t & 63, q = t >> 6;
#pragma unroll
    for (int jj = 0; jj < 16; ++jj) {
        const int b = q * 16 + jj;
        tile[c][b] = x[(size_t)b * XM + (size_t)(m0 + c)];
    }
    __syncthreads();
#pragma unroll
    for (int jj = 0; jj < 16; ++jj) {
        const int m = q * 16 + jj;
        xT[(size_t)(m0 + m) * 64u + (size_t)c] = tile[m][c];
    }
}

__global__ __launch_bounds__(256) void lc2d_main(const float* __restrict__ w,
                                                 const float* __restrict__ xT,
                                                 float* __restrict__ out) {
    // [wave][buf][k][og*8+l] floats; DMA writes lane-linear (dest = base + lane*4).
    // reads: b128 at word og*8 (+4) -> 8 distinct addrs, worst 2-way banks (free).
    __shared__ float Wl[4][2][9][64];   // 18 KiB -> 4 blocks/CU fits easily

    const int bid = blockIdx.x;
    const int t = (bid & 7) * 124 + (bid >> 3);          // XCD chunk swizzle (992 = 8*124)
    const int ohalf = (t >= 496) ? 1 : 0;
    const int rem = t - ohalf * 496;
    const int oh = rem >> 3;
    const int t8 = rem & 7;
    const int ow0 = (t8 < 7) ? (t8 << 3) : 54;           // last tile overlaps: no guards
    const int loc0 = oh * OWDIM + ow0;

    const int lane = threadIdx.x & 63;
    const int wave = __builtin_amdgcn_readfirstlane((int)(threadIdx.x >> 6));
    const int bg = lane & 7;      // b-octet: b = bg*8 + db; staging: loc-sub
    const int og = lane >> 3;     // o within wave's octet;  staging: o-row
    const int o = ohalf * 32 + wave * 8 + og;

    // per-lane weight source: (o, loc0+bg), 9 taps contiguous
    const float* wsrc = w + (size_t)o * 32u * WSI + (size_t)(loc0 + bg) * 9u;
    const float* xbase = xT + (size_t)(bg * 8);

    float4 accA[8], accB[8];
#pragma unroll
    for (int l = 0; l < 8; ++l) {
        accA[l] = make_float4(0.f, 0.f, 0.f, 0.f);
        accB[l] = make_float4(0.f, 0.f, 0.f, 0.f);
    }

    // prologue: stage channel 0 into buf 0
#pragma unroll
    for (int f = 0; f < 9; ++f)
        __builtin_amdgcn_global_load_lds(
            (const __attribute__((address_space(1))) unsigned int*)(wsrc + f),
            (__attribute__((address_space(3))) unsigned int*)&Wl[wave][0][f][0], 4, 0, 0);

#pragma unroll 1
    for (int i = 0; i < 32; ++i) {
        const int buf = i & 1;

        // buf[i]'s DMAs were issued a full channel ago -> near-free drain; makes
        // them ds_read-visible.
        asm volatile("s_waitcnt vmcnt(0)" ::: "memory");
        __builtin_amdgcn_sched_barrier(0);

        if (i < 31) {   // fire next channel's 9 DMAs into the other buffer
            const float* s = wsrc + (size_t)(i + 1) * WSI;
#pragma unroll
            for (int f = 0; f < 9; ++f)
                __builtin_amdgcn_global_load_lds(
                    (const __attribute__((address_space(1))) unsigned int*)(s + f),
                    (__attribute__((address_space(3))) unsigned int*)&Wl[wave][buf ^ 1][f][0], 4, 0, 0);
        }
        __builtin_amdgcn_sched_barrier(0);

        const float* wl = &Wl[wave][buf][0][0];
#pragma unroll
        for (int r = 0; r < 3; ++r) {
            // weight frags for this row's 3 taps (6x ds_read_b128, 24 regs)
            float4 wqa[3], wqb[3];
#pragma unroll
            for (int cc = 0; cc < 3; ++cc) {
                wqa[cc] = *(const float4*)(wl + (r * 3 + cc) * 64 + og * 8);
                wqb[cc] = *(const float4*)(wl + (r * 3 + cc) * 64 + og * 8 + 4);
            }
            const float* xp = xbase + ((size_t)i * 4096u + (size_t)((oh + r) * 64 + ow0)) * 64u;

            // 3-slot static ring, 2-deep prefetch; all indices compile-time.
            float4 Xa[3], Xb[3];
            Xa[0] = *(const float4*)(xp);
            Xb[0] = *(const float4*)(xp + 4);
            Xa[1] = *(const float4*)(xp + 64);
            Xb[1] = *(const float4*)(xp + 68);
#pragma unroll
            for (int m = 0; m < 10; ++m) {
                if (m + 2 < 10) {
                    Xa[(m + 2) % 3] = *(const float4*)(xp + (size_t)((m + 2) * 64));
                    Xb[(m + 2) % 3] = *(const float4*)(xp + (size_t)((m + 2) * 64) + 4);
                }
#pragma unroll
                for (int cc = 0; cc < 3; ++cc) {
                    const int l = m - cc;            // loc' hit by col m at tap-col cc
                    if (l >= 0 && l < 8) {
                        const float ws = (l < 4) ? f4get(wqa[cc], l & 3) : f4get(wqb[cc], l & 3);
                        fma4(accA[l], ws, Xa[m % 3]);
                        fma4(accB[l], ws, Xb[m % 3]);
                    }
                }
                __builtin_amdgcn_sched_barrier(0);   // freeze ring liveness
            }
            __builtin_amdgcn_sched_barrier(0);       // section fence
        }
    }

    // stores: per (b,o) an 8-float loc run -> 4x float2 (loc0 even -> 8B aligned)
#define ACCV(db, l) ((db) < 4 ? f4get(accA[(l)], (db)) : f4get(accB[(l)], (db) - 4))
#pragma unroll
    for (int db = 0; db < 8; ++db) {
        float* po = out + (size_t)((bg * 8 + db) * 64 + o) * (size_t)LOCS + (size_t)loc0;
        *(float2*)(po + 0) = make_float2(ACCV(db, 0), ACCV(db, 1));
        *(float2*)(po + 2) = make_float2(ACCV(db, 2), ACCV(db, 3));
        *(float2*)(po + 4) = make_float2(ACCV(db, 4), ACCV(db, 5));
        *(float2*)(po + 6) = make_float2(ACCV(db, 6), ACCV(db, 7));
    }
#undef ACCV
}

extern "C" void kernel_launch(void* const* d_in, const int* in_sizes, int n_in,
                              void* d_out, int out_size, void* d_ws, size_t ws_size,
                              hipStream_t stream) {
    const float* x = (const float*)d_in[0];   // 64*32*64*64
    const float* w = (const float*)d_in[1];   // 1*64*32*62*62*9
    float* out = (float*)d_out;               // 64*64*62*62
    float* xT = (float*)d_ws;                 // 32 MiB scratch

    lc2d_transpose_x<<<dim3(XM / 64), dim3(256), 0, stream>>>(x, xT);
    lc2d_main<<<dim3(992), dim3(256), 0, stream>>>(w, xT, out);
}